// Round 7
// baseline (1129.122 us; speedup 1.0000x reference)
//
#include <hip/hip_runtime.h>

// Swin-style window attention, fully fused: one main kernel, <=1.2MB workspace.
// Block = one window (64 tokens, C=256, 8 heads x hd=32). 512 threads = 8 waves.
// Wave w: QKV cols for head w -> attention head w -> proj cols [w*32, w*32+32).
// PRE=1: weights pre-split to bf16 hi/lo in ws, bias pre-gathered (needs 2MB ws).
// PRE=0: fully self-contained fallback (zero ws use).
// Numerics: x, weights, V, att all split-bf16 (fp32-faithful ~2^-16); P split-bf16
// (3-term PV); Q/K single-bf16 (logit err ~2e-4; LDS capacity forces this).

#define NBLK 4096
#define SCALE_F 0.17677669529663689f

typedef __attribute__((ext_vector_type(8))) short short8;
typedef __attribute__((ext_vector_type(4))) short s4v;
typedef __attribute__((ext_vector_type(4))) float f32x4;

// ---- LDS map (shorts). Region reuse:
//  [XH_S]  phase A: Xh      phase B: Q (bf16)     phase C: attH
//  [XL_S]  phase A: Xl      phase B: K (bf16)     phase C: attL
//  [VTH_S/VTL_S] V^T split-bf16 [head][d][tok], alive phases A-B (intra-wave only).
#define XSTR 264                 // 256 + 8 pad: row 528B; 16B-aligned, bank-shift 4
#define VSTR 72                  // 64 + 8 pad: row 144B
#define XH_S 0
#define XL_S 16896               // 64*264
#define VTH_S 33792
#define VTL_S 52224              // + 8*32*72
#define LDS_SHORTS 70656         // 141312 B static (< 160 KB group segment; 1 blk/CU)

// ws layout (shorts): wqh[196608] wql[196608] wph[65536] wpl[65536] | biasf f32[32768]
#define WQH_S 0
#define WQL_S 196608
#define WPH_S 393216
#define WPL_S 458752
#define BIASF_BYTE 1048576
#define WS_NEED (2u << 20)

__device__ inline unsigned short f2bf(float x) {
    union { float f; unsigned u; } a; a.f = x;
    unsigned r = a.u + 0x7FFFu + ((a.u >> 16) & 1u);
    return (unsigned short)(r >> 16);
}
__device__ inline float bf2f(unsigned short b) {
    union { unsigned u; float f; } a; a.u = ((unsigned)b) << 16; return a.f;
}
__device__ inline void split8(float4 f0, float4 f1, short8& h, short8& l) {
    float v[8] = { f0.x, f0.y, f0.z, f0.w, f1.x, f1.y, f1.z, f1.w };
    #pragma unroll
    for (int i = 0; i < 8; ++i) {
        unsigned short hi = f2bf(v[i]);
        h[i] = (short)hi;
        l[i] = (short)f2bf(v[i] - bf2f(hi));
    }
}

// ---------------------------------------------------------------------------
// prologue kernels (PRE path only)
// ---------------------------------------------------------------------------
__global__ __launch_bounds__(256)
void presplit_w(const float* __restrict__ qkv_w, const float* __restrict__ proj_w,
                short* __restrict__ wsp)
{
    int idx = blockIdx.x * 256 + threadIdx.x;     // 0..262143
    float v; short *h, *l;
    if (idx < 196608) {
        v = qkv_w[idx];
        h = wsp + WQH_S + idx;  l = wsp + WQL_S + idx;
    } else {
        int j = idx - 196608;
        v = proj_w[j];
        h = wsp + WPH_S + j;    l = wsp + WPL_S + j;
    }
    unsigned short hi = f2bf(v);
    *h = (short)hi;
    *l = (short)f2bf(v - bf2f(hi));
}

__global__ __launch_bounds__(256)
void bias_gather(const float* __restrict__ bt, const int* __restrict__ rl,
                 float* __restrict__ biasf)
{
    int idx = blockIdx.x * 256 + threadIdx.x;     // 0..32767
    int hh  = idx >> 12;
    int rc  = idx & 4095;
    biasf[idx] = bt[rl[rc] * 8 + hh];
}

// ---------------------------------------------------------------------------
template<int PRE>
__global__ __launch_bounds__(512, 2)
void fused_window_attn(const float* __restrict__ x,
                       const float* __restrict__ mask,
                       const float* __restrict__ qkv_w,
                       const float* __restrict__ qkv_b,
                       const float* __restrict__ proj_w,
                       const float* __restrict__ proj_b,
                       const float* __restrict__ bt,
                       const int*   __restrict__ rl,
                       float* __restrict__ out,
                       const short* __restrict__ wqh, const short* __restrict__ wql,
                       const short* __restrict__ wph, const short* __restrict__ wpl,
                       const float* __restrict__ biasf)
{
    __shared__ short lds[LDS_SHORTS];
    short* Xh  = lds + XH_S;     // also Q, attH
    short* Xl  = lds + XL_S;     // also K, attL
    short* Vth = lds + VTH_S;
    short* Vtl = lds + VTL_S;

    const int b    = blockIdx.x;
    const int t    = threadIdx.x;
    const int lane = t & 63;
    const int w    = t >> 6;       // wave id == head id
    const int l15  = lane & 15;
    const int lg   = lane >> 4;    // 0..3

    const f32x4 zz = { 0.f, 0.f, 0.f, 0.f };

    // ---------------- Phase A0: stage x window, split to bf16 hi/lo ----------
    {
        const float* xp = x + (size_t)b * (64 * 256);
        #pragma unroll
        for (int i = 0; i < 8; ++i) {
            int f  = t + i * 512;        // float4 index 0..4095
            int r  = f >> 6;             // token 0..63
            int c4 = f & 63;             // float4 within row
            float4 v0 = *reinterpret_cast<const float4*>(xp + r * 256 + c4 * 4);
            s4v h, l;
            #pragma unroll
            for (int e = 0; e < 4; ++e) {
                float vv = (e == 0) ? v0.x : (e == 1) ? v0.y : (e == 2) ? v0.z : v0.w;
                unsigned short hi = f2bf(vv);
                h[e] = (short)hi;
                l[e] = (short)f2bf(vv - bf2f(hi));
            }
            *reinterpret_cast<s4v*>(&Xh[r * XSTR + c4 * 4]) = h;
            *reinterpret_cast<s4v*>(&Xl[r * XSTR + c4 * 4]) = l;
        }
    }
    __syncthreads();

    // ---------------- Phase A1: QKV GEMM (wave w -> cols of head w) ----------
    // acc[rf][c]: rf = token frag (4x16), c = tau*2+cf (q0,q1,k0,k1,v0,v1)
    f32x4 acc[4][6];
    #pragma unroll
    for (int i = 0; i < 4; ++i)
        #pragma unroll
        for (int j = 0; j < 6; ++j) acc[i][j] = zz;

    for (int s = 0; s < 8; ++s) {
        short8 xh[4], xl[4];
        #pragma unroll
        for (int rf = 0; rf < 4; ++rf) {
            int off = (rf * 16 + l15) * XSTR + s * 32 + lg * 8;
            xh[rf] = *reinterpret_cast<const short8*>(&Xh[off]);
            xl[rf] = *reinterpret_cast<const short8*>(&Xl[off]);
        }
        #pragma unroll
        for (int c = 0; c < 6; ++c) {
            int tau = c >> 1, cf = c & 1;
            int wrow = tau * 256 + w * 32 + cf * 16 + l15;
            short8 bh, bl;
            if constexpr (PRE) {
                size_t wo = (size_t)wrow * 256 + s * 32 + lg * 8;
                bh = *reinterpret_cast<const short8*>(&wqh[wo]);
                bl = *reinterpret_cast<const short8*>(&wql[wo]);
            } else {
                const float* wp = qkv_w + (size_t)wrow * 256 + s * 32 + lg * 8;
                float4 f0 = *reinterpret_cast<const float4*>(wp);
                float4 f1 = *reinterpret_cast<const float4*>(wp + 4);
                split8(f0, f1, bh, bl);
            }
            #pragma unroll
            for (int rf = 0; rf < 4; ++rf) {
                acc[rf][c] = __builtin_amdgcn_mfma_f32_16x16x32_bf16(xh[rf], bh, acc[rf][c], 0, 0, 0);
                acc[rf][c] = __builtin_amdgcn_mfma_f32_16x16x32_bf16(xh[rf], bl, acc[rf][c], 0, 0, 0);
                acc[rf][c] = __builtin_amdgcn_mfma_f32_16x16x32_bf16(xl[rf], bh, acc[rf][c], 0, 0, 0);
            }
        }
    }

    // V writeback (split) into Vt region [head][d][tok] — disjoint from X.
    #pragma unroll
    for (int rf = 0; rf < 4; ++rf)
        #pragma unroll
        for (int cf = 0; cf < 2; ++cf) {
            int d  = cf * 16 + l15;
            float vb = qkv_b[512 + w * 32 + d];
            s4v h4, l4;
            #pragma unroll
            for (int p = 0; p < 4; ++p) {
                float v = acc[rf][4 + cf][p] + vb;
                unsigned short hi = f2bf(v);
                h4[p] = (short)hi;
                l4[p] = (short)f2bf(v - bf2f(hi));
            }
            int off = (w * 32 + d) * VSTR + rf * 16 + lg * 4;
            *reinterpret_cast<s4v*>(&Vth[off]) = h4;
            *reinterpret_cast<s4v*>(&Vtl[off]) = l4;
        }
    __syncthreads();   // all waves done reading X -> X region reusable

    // Q (scaled) and K writeback as single bf16 into X region.
    #pragma unroll
    for (int rf = 0; rf < 4; ++rf)
        #pragma unroll
        for (int cf = 0; cf < 2; ++cf) {
            int d  = cf * 16 + l15;
            int ch = w * 32 + d;
            float qb = qkv_b[ch];
            float kb = qkv_b[256 + ch];
            #pragma unroll
            for (int p = 0; p < 4; ++p) {
                int tok = rf * 16 + lg * 4 + p;
                Xh[tok * XSTR + ch] = (short)f2bf((acc[rf][cf][p] + qb) * SCALE_F);  // Q
                Xl[tok * XSTR + ch] = (short)f2bf(acc[rf][2 + cf][p] + kb);         // K
            }
        }
    __syncthreads();

    // ---------------- Phase B: attention for head w ----------
    // V^T B-fragments (per wave, own head): [df][slab]
    short8 vbh[2][2], vbl[2][2];
    #pragma unroll
    for (int df = 0; df < 2; ++df)
        #pragma unroll
        for (int s = 0; s < 2; ++s) {
            int off = (w * 32 + df * 16 + l15) * VSTR + s * 32 + lg * 8;
            vbh[df][s] = *reinterpret_cast<const short8*>(&Vth[off]);
            vbl[df][s] = *reinterpret_cast<const short8*>(&Vtl[off]);
        }

    // S^T = K @ Q^T : st[ki][qj], C/D: col = q = qj*16+l15, row = kk = ki*16+lg*4+p
    f32x4 st[4][4];
    {
        short8 kf[4], qf[4];
        #pragma unroll
        for (int i = 0; i < 4; ++i) {
            int off = (i * 16 + l15) * XSTR + w * 32 + lg * 8;
            qf[i] = *reinterpret_cast<const short8*>(&Xh[off]);
            kf[i] = *reinterpret_cast<const short8*>(&Xl[off]);
        }
        #pragma unroll
        for (int ki = 0; ki < 4; ++ki)
            #pragma unroll
            for (int qj = 0; qj < 4; ++qj)
                st[ki][qj] = __builtin_amdgcn_mfma_f32_16x16x32_bf16(kf[ki], qf[qj], zz, 0, 0, 0);
    }
    __syncthreads();   // Q/K consumed everywhere -> att region reusable

    // softmax + PV (split-P, 3-term), per q-column-fragment
    f32x4 o[4][2];
    #pragma unroll
    for (int i = 0; i < 4; ++i) { o[i][0] = zz; o[i][1] = zz; }

    const float* mrow_base = mask + (size_t)(b & 63) * 4096;

    #pragma unroll
    for (int qj = 0; qj < 4; ++qj) {
        int q = qj * 16 + l15;
        const float* mrow  = mrow_base + q * 64;
        const int*   rlrow = rl + q * 64;
        const float* brow  = PRE ? (biasf + ((size_t)w * 64 + q) * 64) : nullptr;

        float ev[4][4];
        float mx = -3.0e38f;
        #pragma unroll
        for (int ki = 0; ki < 4; ++ki) {
            int kk0 = ki * 16 + lg * 4;
            float4 mv = *reinterpret_cast<const float4*>(mrow + kk0);
            float bvv[4];
            if constexpr (PRE) {
                float4 b4 = *reinterpret_cast<const float4*>(brow + kk0);
                bvv[0] = b4.x; bvv[1] = b4.y; bvv[2] = b4.z; bvv[3] = b4.w;
            } else {
                #pragma unroll
                for (int p = 0; p < 4; ++p) bvv[p] = bt[rlrow[kk0 + p] * 8 + w];
            }
            float mvv[4] = { mv.x, mv.y, mv.z, mv.w };
            #pragma unroll
            for (int p = 0; p < 4; ++p) {
                float lv = st[ki][qj][p] + mvv[p] + bvv[p];
                ev[ki][p] = lv;
                mx = fmaxf(mx, lv);
            }
        }
        mx = fmaxf(mx, __shfl_xor(mx, 16));
        mx = fmaxf(mx, __shfl_xor(mx, 32));
        float sm = 0.f;
        #pragma unroll
        for (int ki = 0; ki < 4; ++ki)
            #pragma unroll
            for (int p = 0; p < 4; ++p) {
                float e = __expf(ev[ki][p] - mx);
                ev[ki][p] = e;
                sm += e;
            }
        sm += __shfl_xor(sm, 16);
        sm += __shfl_xor(sm, 32);
        float rs = 1.0f / sm;

        // pack P split-bf16 : pk*[ki][pp] covers kk = ki*16 + lg*4 + 2*pp (+1)
        unsigned pkh[4][2], pkl[4][2];
        #pragma unroll
        for (int ki = 0; ki < 4; ++ki)
            #pragma unroll
            for (int pp = 0; pp < 2; ++pp) {
                float v0 = ev[ki][2 * pp] * rs;
                float v1 = ev[ki][2 * pp + 1] * rs;
                unsigned h0 = f2bf(v0), h1 = f2bf(v1);
                unsigned l0 = f2bf(v0 - bf2f((unsigned short)h0));
                unsigned l1 = f2bf(v1 - bf2f((unsigned short)h1));
                pkh[ki][pp] = h0 | (h1 << 16);
                pkl[ki][pp] = l0 | (l1 << 16);
            }

        // assemble P A-fragments: lane needs kk = 32s + 8lg + j (j=0..7)
        // u32 slot tt: pair base kk = 32s+8lg+2tt -> ki = 2s+(lg>>1), pp = tt&1,
        // src group g = (2lg + (tt>>1)) & 3, src lane = l15 + 16g.  (verified:
        // fetched k = 32s+16(lg>>1)+4g+2(tt&1) == 32s+8lg+2tt for all lg,tt)
        #pragma unroll
        for (int s = 0; s < 2; ++s) {
            unsigned pah[4], pal[4];
            #pragma unroll
            for (int tt = 0; tt < 4; ++tt) {
                int g   = (2 * lg + (tt >> 1)) & 3;
                int src = l15 + 16 * g;
                unsigned h0 = (unsigned)__shfl((int)pkh[2 * s][tt & 1], src);
                unsigned h1 = (unsigned)__shfl((int)pkh[2 * s + 1][tt & 1], src);
                unsigned l0 = (unsigned)__shfl((int)pkl[2 * s][tt & 1], src);
                unsigned l1 = (unsigned)__shfl((int)pkl[2 * s + 1][tt & 1], src);
                pah[tt] = (lg >> 1) ? h1 : h0;
                pal[tt] = (lg >> 1) ? l1 : l0;
            }
            union { unsigned u[4]; short8 s8; } ch_, cl_;
            ch_.u[0] = pah[0]; ch_.u[1] = pah[1]; ch_.u[2] = pah[2]; ch_.u[3] = pah[3];
            cl_.u[0] = pal[0]; cl_.u[1] = pal[1]; cl_.u[2] = pal[2]; cl_.u[3] = pal[3];
            short8 pafh = ch_.s8, pafl = cl_.s8;
            #pragma unroll
            for (int df = 0; df < 2; ++df) {
                o[qj][df] = __builtin_amdgcn_mfma_f32_16x16x32_bf16(pafh, vbh[df][s], o[qj][df], 0, 0, 0);
                o[qj][df] = __builtin_amdgcn_mfma_f32_16x16x32_bf16(pafh, vbl[df][s], o[qj][df], 0, 0, 0);
                o[qj][df] = __builtin_amdgcn_mfma_f32_16x16x32_bf16(pafl, vbh[df][s], o[qj][df], 0, 0, 0);
            }
        }
    }

    // att writeback (split bf16) into att region = old Q/K space.
    // o C/D: col(d) = df*16+l15, row(q) = qj*16+lg*4+p.
    #pragma unroll
    for (int qj = 0; qj < 4; ++qj)
        #pragma unroll
        for (int df = 0; df < 2; ++df) {
            int ch = w * 32 + df * 16 + l15;
            #pragma unroll
            for (int p = 0; p < 4; ++p) {
                int q = qj * 16 + lg * 4 + p;
                float v = o[qj][df][p];
                unsigned short hi = f2bf(v);
                Xh[q * XSTR + ch] = (short)hi;                    // attH
                Xl[q * XSTR + ch] = (short)f2bf(v - bf2f(hi));    // attL
            }
        }
    __syncthreads();   // cross-wave: proj reads ALL channels

    // ---------------- Phase C: proj GEMM (wave w -> out cols w*32..w*32+31) ----
    f32x4 pacc[4][2];
    #pragma unroll
    for (int i = 0; i < 4; ++i) { pacc[i][0] = zz; pacc[i][1] = zz; }

    for (int s = 0; s < 8; ++s) {
        short8 ah[4], al[4];
        #pragma unroll
        for (int rf = 0; rf < 4; ++rf) {
            int off = (rf * 16 + l15) * XSTR + s * 32 + lg * 8;
            ah[rf] = *reinterpret_cast<const short8*>(&Xh[off]);
            al[rf] = *reinterpret_cast<const short8*>(&Xl[off]);
        }
        #pragma unroll
        for (int cf = 0; cf < 2; ++cf) {
            int wrow = w * 32 + cf * 16 + l15;
            short8 bh, bl;
            if constexpr (PRE) {
                size_t wo = (size_t)wrow * 256 + s * 32 + lg * 8;
                bh = *reinterpret_cast<const short8*>(&wph[wo]);
                bl = *reinterpret_cast<const short8*>(&wpl[wo]);
            } else {
                const float* wp = proj_w + (size_t)wrow * 256 + s * 32 + lg * 8;
                float4 f0 = *reinterpret_cast<const float4*>(wp);
                float4 f1 = *reinterpret_cast<const float4*>(wp + 4);
                split8(f0, f1, bh, bl);
            }
            #pragma unroll
            for (int rf = 0; rf < 4; ++rf) {
                pacc[rf][cf] = __builtin_amdgcn_mfma_f32_16x16x32_bf16(ah[rf], bh, pacc[rf][cf], 0, 0, 0);
                pacc[rf][cf] = __builtin_amdgcn_mfma_f32_16x16x32_bf16(ah[rf], bl, pacc[rf][cf], 0, 0, 0);
                pacc[rf][cf] = __builtin_amdgcn_mfma_f32_16x16x32_bf16(al[rf], bh, pacc[rf][cf], 0, 0, 0);
            }
        }
    }

    float* op = out + (size_t)b * (64 * 256);
    #pragma unroll
    for (int rf = 0; rf < 4; ++rf)
        #pragma unroll
        for (int cf = 0; cf < 2; ++cf) {
            int col = w * 32 + cf * 16 + l15;
            float pb = proj_b[col];
            #pragma unroll
            for (int p = 0; p < 4; ++p) {
                int row = rf * 16 + lg * 4 + p;
                op[row * 256 + col] = pacc[rf][cf][p] + pb;
            }
        }
}

// ---------------------------------------------------------------------------
extern "C" void kernel_launch(void* const* d_in, const int* in_sizes, int n_in,
                              void* d_out, int out_size, void* d_ws, size_t ws_size,
                              hipStream_t stream)
{
    const float* x          = (const float*)d_in[0];
    const float* mask       = (const float*)d_in[1];
    const float* qkv_w      = (const float*)d_in[2];
    const float* qkv_b      = (const float*)d_in[3];
    const float* proj_w     = (const float*)d_in[4];
    const float* proj_b     = (const float*)d_in[5];
    const float* bias_table = (const float*)d_in[6];
    const int*   rl_ind     = (const int*)d_in[7];
    float*       out        = (float*)d_out;

    if (ws_size >= (size_t)WS_NEED) {
        short* wsp   = (short*)d_ws;
        float* biasf = (float*)((char*)d_ws + BIASF_BYTE);
        presplit_w<<<dim3(1024), dim3(256), 0, stream>>>(qkv_w, proj_w, wsp);
        bias_gather<<<dim3(128), dim3(256), 0, stream>>>(bias_table, rl_ind, biasf);
        fused_window_attn<1><<<dim3(NBLK), dim3(512), 0, stream>>>(
            x, mask, qkv_w, qkv_b, proj_w, proj_b, bias_table, rl_ind, out,
            wsp + WQH_S, wsp + WQL_S, wsp + WPH_S, wsp + WPL_S, biasf);
    } else {
        fused_window_attn<0><<<dim3(NBLK), dim3(512), 0, stream>>>(
            x, mask, qkv_w, qkv_b, proj_w, proj_b, bias_table, rl_ind, out,
            nullptr, nullptr, nullptr, nullptr, nullptr);
    }
}